// Round 3
// baseline (66.600 us; speedup 1.0000x reference)
//
#include <hip/hip_runtime.h>

#define N_NODES 30000
#define C 128
#define E_EDGES 480000
#define BM 64

typedef __attribute__((ext_vector_type(8))) short bf16x8;
typedef __attribute__((ext_vector_type(4))) float f32x4;

// ws layout:
//   bytes [0, 131072)            : Bt bf16 [set][256 cols][128 k]  (set*65536 B)
//   float offset 32768 + set*256 : cv f32 [set][256]
//   float offset 33280 + g*N     : masks f32 [4][N]  g: 0=graph1,1=graph21,2=graph2,3=graph12
#define CV_OFF_F(set) (32768 + (set) * 256)
#define MASK_OFF_F(g) (33280 + (g) * N_NODES)

__device__ __forceinline__ unsigned short f2bf(float f) {
  union { float f; unsigned int u; } v; v.f = f;
  unsigned int r = v.u + 0x7FFF + ((v.u >> 16) & 1);  // RNE
  return (unsigned short)(r >> 16);
}

// ---------------------------------------------------------------------------
// K1: fused prep (blockIdx.x < 128) + mask zeroing (blockIdx.x >= 128)
//   prep: Bt[set][j][k] = sum_c wv[c][k] * wp[j&127][(j<128?c:128+c)] (bf16)
//         cv[set][j]    = sum_c bv[c]    * wp[...]                    (f32)
//   zero: y=0 zeros masks g0,g1; y=1 zeros g2,g3 (60000 floats each)
// grid (128 + 235, 2), block 256
// ---------------------------------------------------------------------------
__global__ void prep_zero_kernel(const float* __restrict__ wv1, const float* __restrict__ bv1,
                                 const float* __restrict__ wp1,
                                 const float* __restrict__ wv2, const float* __restrict__ bv2,
                                 const float* __restrict__ wp2,
                                 float* __restrict__ ws) {
  const int set = blockIdx.y;
  if (blockIdx.x >= 128) {
    const int idx = (blockIdx.x - 128) * 256 + threadIdx.x;
    if (idx < 2 * N_NODES) ws[33280 + set * 2 * N_NODES + idx] = 0.f;
    return;
  }
  const int k = blockIdx.x;  // 0..127
  const float* wv = set ? wv2 : wv1;
  const float* bv = set ? bv2 : bv1;
  const float* wp = set ? wp2 : wp1;

  __shared__ float wvcol[C];
  const int t = threadIdx.x;
  if (t < C) wvcol[t] = wv[t * C + k];
  __syncthreads();

  const int j = t;  // 0..255
  const float* wprow = wp + (j & 127) * (2 * C) + ((j < C) ? 0 : C);
  float s = 0.f;
#pragma unroll 4
  for (int c = 0; c < C; ++c) s += wvcol[c] * wprow[c];
  unsigned short* bt = (unsigned short*)ws;
  bt[set * 32768 + j * 128 + k] = f2bf(s);

  if (k == 0) {
    float s2 = 0.f;
#pragma unroll 4
    for (int c = 0; c < C; ++c) s2 += bv[c] * wprow[c];
    ws[CV_OFF_F(set) + j] = s2;
  }
}

// ---------------------------------------------------------------------------
// K2: scatter membership masks
// ---------------------------------------------------------------------------
__global__ void scatter_masks(const int* __restrict__ g1, const int* __restrict__ g21,
                              const int* __restrict__ g2, const int* __restrict__ g12,
                              float* __restrict__ ws) {
  const int e = blockIdx.x * 256 + threadIdx.x;
  if (e >= E_EDGES) return;
  const int g = blockIdx.y;
  const int* gp = (g == 0) ? g1 : (g == 1) ? g21 : (g == 2) ? g2 : g12;
  ws[MASK_OFF_F(g) + gp[e]] = 1.0f;  // idempotent
}

// ---------------------------------------------------------------------------
// K3: LDS-free main. Per set: T = feat(bf16) @ Bt^T via MFMA.
//   A: direct global f32 loads (16 rows x 128B lines per wave-instr, line-coalesced),
//      converted to bf16 in-reg. OOB rows clamped (stores guarded).
//   B: bf16x8 direct loads from ws (L2-resident, 128 KB), reg double-buffered.
// grid (ceil(N/64), 2), block 512 (8 waves = 2M x 4J).
// ---------------------------------------------------------------------------
__global__ __launch_bounds__(512, 4) void main_kernel(
    const float* __restrict__ feat1, const float* __restrict__ feat2,
    const float* __restrict__ bp1, const float* __restrict__ bp2,
    const float* __restrict__ ws, float* __restrict__ out) {
  const int set = blockIdx.y;
  const float* feat = set ? feat2 : feat1;
  const float* bp   = set ? bp2 : bp1;
  const unsigned short* Bt = (const unsigned short*)ws + (size_t)set * 32768;
  const float* cv = ws + CV_OFF_F(set);
  const float* mA = ws + MASK_OFF_F(2 * set);
  const float* mB = ws + MASK_OFF_F(2 * set + 1);
  float* outp = out + (size_t)set * N_NODES * C;

  const int i0 = blockIdx.x * BM;
  const int tid = threadIdx.x;
  const int wave = tid >> 6;   // 0..7
  const int lane = tid & 63;
  const int wm = wave >> 2;    // 0..1 -> rows [wm*32, +32)
  const int wj = wave & 3;     // 0..3 -> jj   [wj*32, +32)
  const int l15 = lane & 15;
  const int lk  = lane >> 4;   // 0..3

  // B base for this lane: col = wj*32 + nt*16 + h*128 + l15; k-chunk = ks*32 + lk*8
  const unsigned short* bbase = Bt + (size_t)(wj * 32 + l15) * 128 + lk * 8;

  // prefetch ks=0 B frags
  bf16x8 breg[2][2][2];  // [buf][nt][h]
#pragma unroll
  for (int nt = 0; nt < 2; ++nt)
#pragma unroll
    for (int h = 0; h < 2; ++h)
      breg[0][nt][h] = *reinterpret_cast<const bf16x8*>(bbase + (nt * 16 + h * 128) * 128);

  // A row indices (clamped; OOB rows computed but never stored)
  int rowA[2];
#pragma unroll
  for (int mt = 0; mt < 2; ++mt) {
    const int gi = i0 + wm * 32 + mt * 16 + l15;
    rowA[mt] = (gi < N_NODES) ? gi : (N_NODES - 1);
  }

  f32x4 acc[2][2][2] = {};  // [mt][nt][half]

#pragma unroll
  for (int ks = 0; ks < 4; ++ks) {
    // load + convert A fragments (k = ks*32 + lk*8 .. +7)
    bf16x8 a[2];
#pragma unroll
    for (int mt = 0; mt < 2; ++mt) {
      const float* p = feat + (size_t)rowA[mt] * C + ks * 32 + lk * 8;
      const float4 v0 = *reinterpret_cast<const float4*>(p);
      const float4 v1 = *reinterpret_cast<const float4*>(p + 4);
      bf16x8 t;
      t[0] = (short)f2bf(v0.x); t[1] = (short)f2bf(v0.y);
      t[2] = (short)f2bf(v0.z); t[3] = (short)f2bf(v0.w);
      t[4] = (short)f2bf(v1.x); t[5] = (short)f2bf(v1.y);
      t[6] = (short)f2bf(v1.z); t[7] = (short)f2bf(v1.w);
      a[mt] = t;
    }
    // prefetch next-ks B frags
    if (ks < 3) {
#pragma unroll
      for (int nt = 0; nt < 2; ++nt)
#pragma unroll
        for (int h = 0; h < 2; ++h)
          breg[(ks + 1) & 1][nt][h] =
              *reinterpret_cast<const bf16x8*>(bbase + (nt * 16 + h * 128) * 128 + (ks + 1) * 32);
    }
#pragma unroll
    for (int mt = 0; mt < 2; ++mt)
#pragma unroll
      for (int nt = 0; nt < 2; ++nt)
#pragma unroll
        for (int h = 0; h < 2; ++h)
          acc[mt][nt][h] = __builtin_amdgcn_mfma_f32_16x16x32_bf16(
              a[mt], breg[ks & 1][nt][h], acc[mt][nt][h], 0, 0, 0);
  }

  // ---- epilogue: out[i][jj] = hA*(TA+cv[jj]) + hB*(TB+cv[jj+128]) + bp[jj] ----
  float cvA[2], cvB[2], bpv[2];
#pragma unroll
  for (int nt = 0; nt < 2; ++nt) {
    const int jj = wj * 32 + nt * 16 + l15;
    cvA[nt] = cv[jj];
    cvB[nt] = cv[jj + 128];
    bpv[nt] = bp[jj];
  }
#pragma unroll
  for (int mt = 0; mt < 2; ++mt) {
#pragma unroll
    for (int r = 0; r < 4; ++r) {
      const int i = i0 + wm * 32 + mt * 16 + lk * 4 + r;
      if (i >= N_NODES) continue;
      const float hA = mA[i];
      const float hB = mB[i];
#pragma unroll
      for (int nt = 0; nt < 2; ++nt) {
        const int jj = wj * 32 + nt * 16 + l15;
        const float val = hA * (acc[mt][nt][0][r] + cvA[nt]) +
                          hB * (acc[mt][nt][1][r] + cvB[nt]) + bpv[nt];
        outp[(size_t)i * C + jj] = val;
      }
    }
  }
}

// ---------------------------------------------------------------------------
extern "C" void kernel_launch(void* const* d_in, const int* in_sizes, int n_in,
                              void* d_out, int out_size, void* d_ws, size_t ws_size,
                              hipStream_t stream) {
  const float* feat1 = (const float*)d_in[0];
  const float* feat2 = (const float*)d_in[2];
  const float* wv1 = (const float*)d_in[20];
  const float* bv1 = (const float*)d_in[21];
  const float* wv2 = (const float*)d_in[22];
  const float* bv2 = (const float*)d_in[23];
  const float* wp1 = (const float*)d_in[24];
  const float* bp1 = (const float*)d_in[25];
  const float* wp2 = (const float*)d_in[26];
  const float* bp2 = (const float*)d_in[27];
  const int* graph1  = (const int*)d_in[28];
  const int* graph2  = (const int*)d_in[29];
  const int* graph12 = (const int*)d_in[30];
  const int* graph21 = (const int*)d_in[31];

  float* ws = (float*)d_ws;
  float* out = (float*)d_out;

  // K1: fused weights + mask zeroing (235 zero-blocks cover 60000 floats per y)
  prep_zero_kernel<<<dim3(128 + 235, 2), 256, 0, stream>>>(wv1, bv1, wp1, wv2, bv2, wp2, ws);
  // K2: scatter membership (graph[0] = first E ints of each (2,E) array)
  scatter_masks<<<dim3((E_EDGES + 255) / 256, 4), 256, 0, stream>>>(graph1, graph21, graph2, graph12, ws);
  // K3: LDS-free masked fused GEMM + epilogue
  main_kernel<<<dim3((N_NODES + BM - 1) / BM, 2), 512, 0, stream>>>(
      feat1, feat2, bp1, bp2, ws, out);
}

// Round 4
// 55.861 us; speedup vs baseline: 1.1922x; 1.1922x over previous
//
#include <hip/hip_runtime.h>

#define N_NODES 30000
#define C 128
#define E_EDGES 480000
#define BM 64

typedef __attribute__((ext_vector_type(8))) short bf16x8;
typedef __attribute__((ext_vector_type(4))) float f32x4;

// ws layout:
//   bytes [0, 131072)            : Bt bf16 [set][256 cols][128 k]  (set*65536 B)
//   float offset 32768 + set*256 : cv f32 [set][256]
//   float offset 33280 + g*N     : masks f32 [4][N]  g: 0=graph1,1=graph21,2=graph2,3=graph12
#define CV_OFF_F(set) (32768 + (set) * 256)
#define MASK_OFF_F(g) (33280 + (g) * N_NODES)

__device__ __forceinline__ unsigned short f2bf(float f) {
  union { float f; unsigned int u; } v; v.f = f;
  unsigned int r = v.u + 0x7FFF + ((v.u >> 16) & 1);  // RNE
  return (unsigned short)(r >> 16);
}

// ---------------------------------------------------------------------------
// K1: fused prep (blockIdx.x < 128) + mask zeroing (blockIdx.x >= 128)
// grid (128 + 235, 2), block 256
// ---------------------------------------------------------------------------
__global__ void prep_zero_kernel(const float* __restrict__ wv1, const float* __restrict__ bv1,
                                 const float* __restrict__ wp1,
                                 const float* __restrict__ wv2, const float* __restrict__ bv2,
                                 const float* __restrict__ wp2,
                                 float* __restrict__ ws) {
  const int set = blockIdx.y;
  if (blockIdx.x >= 128) {
    const int idx = (blockIdx.x - 128) * 256 + threadIdx.x;
    if (idx < 2 * N_NODES) ws[33280 + set * 2 * N_NODES + idx] = 0.f;
    return;
  }
  const int k = blockIdx.x;  // 0..127
  const float* wv = set ? wv2 : wv1;
  const float* bv = set ? bv2 : bv1;
  const float* wp = set ? wp2 : wp1;

  __shared__ float wvcol[C];
  const int t = threadIdx.x;
  if (t < C) wvcol[t] = wv[t * C + k];
  __syncthreads();

  const int j = t;  // 0..255
  const float* wprow = wp + (j & 127) * (2 * C) + ((j < C) ? 0 : C);
  float s = 0.f;
#pragma unroll 4
  for (int c = 0; c < C; ++c) s += wvcol[c] * wprow[c];
  unsigned short* bt = (unsigned short*)ws;
  bt[set * 32768 + j * 128 + k] = f2bf(s);

  if (k == 0) {
    float s2 = 0.f;
#pragma unroll 4
    for (int c = 0; c < C; ++c) s2 += bv[c] * wprow[c];
    ws[CV_OFF_F(set) + j] = s2;
  }
}

// ---------------------------------------------------------------------------
// K2: scatter membership masks
// ---------------------------------------------------------------------------
__global__ void scatter_masks(const int* __restrict__ g1, const int* __restrict__ g21,
                              const int* __restrict__ g2, const int* __restrict__ g12,
                              float* __restrict__ ws) {
  const int e = blockIdx.x * 256 + threadIdx.x;
  if (e >= E_EDGES) return;
  const int g = blockIdx.y;
  const int* gp = (g == 0) ? g1 : (g == 1) ? g21 : (g == 2) ? g2 : g12;
  ws[MASK_OFF_F(g) + gp[e]] = 1.0f;  // idempotent
}

// ---------------------------------------------------------------------------
// K3: main. A staged in LDS (16 KB, bf16, XOR-swizzled); B streamed from L2
// into a register double-buffer (no B LDS staging -> occupancy up).
// grid (ceil(N/64), 2), block 512 (8 waves = 2M x 4J).
// ---------------------------------------------------------------------------
__global__ __launch_bounds__(512, 4) void main_kernel(
    const float* __restrict__ feat1, const float* __restrict__ feat2,
    const float* __restrict__ bp1, const float* __restrict__ bp2,
    const float* __restrict__ ws, float* __restrict__ out) {
  const int set = blockIdx.y;
  const float* feat = set ? feat2 : feat1;
  const float* bp   = set ? bp2 : bp1;
  const unsigned short* Bt = (const unsigned short*)ws + (size_t)set * 32768;
  const float* cv = ws + CV_OFF_F(set);
  const float* mA = ws + MASK_OFF_F(2 * set);
  const float* mB = ws + MASK_OFF_F(2 * set + 1);
  float* outp = out + (size_t)set * N_NODES * C;

  __shared__ unsigned short feat_s[BM * 128];   // 16 KB

  const int i0 = blockIdx.x * BM;
  const int tid = threadIdx.x;
  const int wave = tid >> 6;   // 0..7
  const int lane = tid & 63;
  const int wm = wave >> 2;    // 0..1 -> rows [wm*32, +32)
  const int wj = wave & 3;     // 0..3 -> jj   [wj*32, +32)
  const int l15 = lane & 15;
  const int lk  = lane >> 4;   // 0..3

  // ---- B register double-buffer, streamed from L2 ----
  // col = wj*32 + nt*16 + h*128 + l15; k-chunk = ks*32 + lk*8
  const unsigned short* bbase = Bt + (size_t)(wj * 32 + l15) * 128 + lk * 8;
  bf16x8 breg[2][2][2];  // [buf][nt][h]
#pragma unroll
  for (int nt = 0; nt < 2; ++nt)
#pragma unroll
    for (int h = 0; h < 2; ++h)
      breg[0][nt][h] = *reinterpret_cast<const bf16x8*>(bbase + (nt * 16 + h * 128) * 128);

  // ---- stage feat tile: 64 rows x 128 cols, f32 -> bf16, swizzled ----
#pragma unroll
  for (int l = 0; l < 4; ++l) {
    const int idx = tid + 512 * l;       // 0..2047
    const int r = idx >> 5;              // row 0..63
    const int q = idx & 31;              // float4 group
    float4 v = make_float4(0.f, 0.f, 0.f, 0.f);
    if (i0 + r < N_NODES) v = reinterpret_cast<const float4*>(feat + (size_t)(i0 + r) * C)[q];
    ushort4 h4;
    h4.x = f2bf(v.x); h4.y = f2bf(v.y); h4.z = f2bf(v.z); h4.w = f2bf(v.w);
    int byte = r * 256 + q * 8;
    byte ^= ((r & 7) << 4);
    *reinterpret_cast<ushort4*>(reinterpret_cast<char*>(feat_s) + byte) = h4;
  }
  __syncthreads();

  f32x4 acc[2][2][2] = {};     // [mt][nt][half]

#pragma unroll
  for (int ks = 0; ks < 4; ++ks) {
    bf16x8 a[2];
#pragma unroll
    for (int mt = 0; mt < 2; ++mt) {
      const int row = wm * 32 + mt * 16 + l15;
      int byte = row * 256 + ks * 64 + lk * 16;
      byte ^= ((row & 7) << 4);
      a[mt] = *reinterpret_cast<const bf16x8*>(reinterpret_cast<const char*>(feat_s) + byte);
    }
    // prefetch next-ks B frags from L2
    if (ks < 3) {
#pragma unroll
      for (int nt = 0; nt < 2; ++nt)
#pragma unroll
        for (int h = 0; h < 2; ++h)
          breg[(ks + 1) & 1][nt][h] =
              *reinterpret_cast<const bf16x8*>(bbase + (nt * 16 + h * 128) * 128 + (ks + 1) * 32);
    }
#pragma unroll
    for (int mt = 0; mt < 2; ++mt)
#pragma unroll
      for (int nt = 0; nt < 2; ++nt)
#pragma unroll
        for (int h = 0; h < 2; ++h)
          acc[mt][nt][h] = __builtin_amdgcn_mfma_f32_16x16x32_bf16(
              a[mt], breg[ks & 1][nt][h], acc[mt][nt][h], 0, 0, 0);
  }

  // ---- epilogue: out[i][jj] = hA*(TA+cv[jj]) + hB*(TB+cv[jj+128]) + bp[jj] ----
  float cvA[2], cvB[2], bpv[2];
#pragma unroll
  for (int nt = 0; nt < 2; ++nt) {
    const int jj = wj * 32 + nt * 16 + l15;
    cvA[nt] = cv[jj];
    cvB[nt] = cv[jj + 128];
    bpv[nt] = bp[jj];
  }
#pragma unroll
  for (int mt = 0; mt < 2; ++mt) {
#pragma unroll
    for (int r = 0; r < 4; ++r) {
      const int i = i0 + wm * 32 + mt * 16 + lk * 4 + r;
      if (i >= N_NODES) continue;
      const float hA = mA[i];
      const float hB = mB[i];
#pragma unroll
      for (int nt = 0; nt < 2; ++nt) {
        const int jj = wj * 32 + nt * 16 + l15;
        const float val = hA * (acc[mt][nt][0][r] + cvA[nt]) +
                          hB * (acc[mt][nt][1][r] + cvB[nt]) + bpv[nt];
        outp[(size_t)i * C + jj] = val;
      }
    }
  }
}

// ---------------------------------------------------------------------------
extern "C" void kernel_launch(void* const* d_in, const int* in_sizes, int n_in,
                              void* d_out, int out_size, void* d_ws, size_t ws_size,
                              hipStream_t stream) {
  const float* feat1 = (const float*)d_in[0];
  const float* feat2 = (const float*)d_in[2];
  const float* wv1 = (const float*)d_in[20];
  const float* bv1 = (const float*)d_in[21];
  const float* wv2 = (const float*)d_in[22];
  const float* bv2 = (const float*)d_in[23];
  const float* wp1 = (const float*)d_in[24];
  const float* bp1 = (const float*)d_in[25];
  const float* wp2 = (const float*)d_in[26];
  const float* bp2 = (const float*)d_in[27];
  const int* graph1  = (const int*)d_in[28];
  const int* graph2  = (const int*)d_in[29];
  const int* graph12 = (const int*)d_in[30];
  const int* graph21 = (const int*)d_in[31];

  float* ws = (float*)d_ws;
  float* out = (float*)d_out;

  prep_zero_kernel<<<dim3(128 + 235, 2), 256, 0, stream>>>(wv1, bv1, wp1, wv2, bv2, wp2, ws);
  scatter_masks<<<dim3((E_EDGES + 255) / 256, 4), 256, 0, stream>>>(graph1, graph21, graph2, graph12, ws);
  main_kernel<<<dim3((N_NODES + BM - 1) / BM, 2), 512, 0, stream>>>(
      feat1, feat2, bp1, bp2, ws, out);
}